// Round 7
// baseline (282.448 us; speedup 1.0000x reference)
//
#include <hip/hip_runtime.h>

typedef unsigned short u16;
typedef unsigned int   u32;
typedef __bf16  bf16x8 __attribute__((ext_vector_type(8)));
typedef float   f32x4  __attribute__((ext_vector_type(4)));
typedef u16     u16x4  __attribute__((ext_vector_type(4)));
typedef u16     u16x8  __attribute__((ext_vector_type(8)));

#define S_LEN 2048
#define NH 32
#define NKVH 8
#define HD 128
#define QKVST 6144          /* packed QKV row stride  */
#define AOST  4096          /* attn-out row stride    */
#define ATT_SCALE 0.08838834764831845f
#define RESCALE_THR 8.0f

__device__ __forceinline__ u16 f2bf(float f){
  u32 u = __builtin_bit_cast(u32, f);
  u += 0x7FFFu + ((u >> 16) & 1u);
  return (u16)(u >> 16);
}
__device__ __forceinline__ float bf2f(u16 h){
  u32 u = ((u32)h) << 16;
  return __builtin_bit_cast(float, u);
}
// async global->LDS, 16B per lane. Dest must be wave-uniform base + lane*16.
__device__ __forceinline__ void gload_lds16(const u16* g, u16* l){
  __builtin_amdgcn_global_load_lds(
      (const __attribute__((address_space(1))) void*)g,
      (__attribute__((address_space(3))) void*)l, 16, 0, 0);
}

// ------------- fused f32 -> bf16 convert of ALL inputs (one launch) --------
// ws layout is contiguous & source-ordered: XB | Wq | Wk | Wv | Wo
__global__ void cvt_all_kernel(const f32x4* __restrict__ hs, const f32x4* __restrict__ wq,
                               const f32x4* __restrict__ wk, const f32x4* __restrict__ wv,
                               const f32x4* __restrict__ wo, u16x4* __restrict__ out){
  int i = blockIdx.x * 256 + threadIdx.x;          // 0 .. 6291455
  const f32x4* src; int off;
  if      (i < 1048576){ src = hs; off = i; }
  else if (i < 3145728){ src = wq; off = i - 1048576; }
  else if (i < 3670016){ src = wk; off = i - 3145728; }
  else if (i < 4194304){ src = wv; off = i - 3670016; }
  else                 { src = wo; off = i - 4194304; }
  f32x4 v = src[off];
  u16x4 o;
  o[0] = f2bf(v[0]); o[1] = f2bf(v[1]); o[2] = f2bf(v[2]); o[3] = f2bf(v[3]);
  out[i] = o;
}

// ---------------- GEMM: C[M][N] = X[M][K] @ W[N][K]^T (bf16 in, f32 acc) ----
// 128x128 tile, BK=64 (2x [128][32] sub-tiles), double-buffered prefetch.
// ROPE=1 fuses partial RoPE (Q+K cols, n0<5120) and ATT_SCALE (Q cols, n0<4096).
template<int OUT_BF16, int ROPE>
__global__ __launch_bounds__(256, 2)
void gemm_bt_kernel(const u16* __restrict__ X, const u16* __restrict__ W,
                    void* __restrict__ Cv, int M, int N, int K,
                    const float* __restrict__ cosv, const float* __restrict__ sinv){
  __shared__ __align__(16) u16 As[2][2][128 * 32];
  __shared__ __align__(16) u16 Bs[2][2][128 * 32];
  const int m0 = blockIdx.y * 128, n0 = blockIdx.x * 128;
  const int tid = threadIdx.x;
  const int wave = tid >> 6, lane = tid & 63;
  const int wm = wave >> 1, wn = wave & 1;
  const int g = lane >> 4, ln = lane & 15;
  const int r0 = tid >> 2;            // rows 0..63 (tid*16B == linear LDS dest)
  const int cc = (tid & 3) * 8;       // bf16 col within sub-tile BK=32
  f32x4 acc[4][4] = {};
  const u16* xa0 = X + (size_t)(m0 + r0) * K + cc;
  const u16* xa1 = X + (size_t)(m0 + r0 + 64) * K + cc;
  const u16* wb0 = W + (size_t)(n0 + r0) * K + cc;
  const u16* wb1 = W + (size_t)(n0 + r0 + 64) * K + cc;

  auto stage = [&](int buf, int k0){
    #pragma unroll
    for (int s = 0; s < 2; s++){
      const int kc = k0 + s * 32;
      gload_lds16(xa0 + kc, &As[buf][s][tid * 8]);
      gload_lds16(xa1 + kc, &As[buf][s][2048 + tid * 8]);
      gload_lds16(wb0 + kc, &Bs[buf][s][tid * 8]);
      gload_lds16(wb1 + kc, &Bs[buf][s][2048 + tid * 8]);
    }
  };

  stage(0, 0);
  __syncthreads();                       // implicit vmcnt(0): tile 0 ready
  int cur = 0;
  for (int k0 = 0; k0 < K; k0 += 64){
    if (k0 + 64 < K) stage(cur ^ 1, k0 + 64);   // prefetch overlaps compute
    #pragma unroll
    for (int s = 0; s < 2; s++){
      bf16x8 a[4], b[4];
      #pragma unroll
      for (int f = 0; f < 4; f++) a[f] = *(const bf16x8*)&As[cur][s][(wm * 64 + f * 16 + ln) * 32 + g * 8];
      #pragma unroll
      for (int f = 0; f < 4; f++) b[f] = *(const bf16x8*)&Bs[cur][s][(wn * 64 + f * 16 + ln) * 32 + g * 8];
      __builtin_amdgcn_s_setprio(1);
      #pragma unroll
      for (int i = 0; i < 4; i++)
        #pragma unroll
        for (int j = 0; j < 4; j++)
          acc[i][j] = __builtin_amdgcn_mfma_f32_16x16x32_bf16(a[i], b[j], acc[i][j], 0, 0, 0);
      __builtin_amdgcn_s_setprio(0);
    }
    __syncthreads();   // ONE barrier/tile: drains prefetch vmcnt + guards reuse
    cur ^= 1;
  }
  if (ROPE){
    // fused partial RoPE: Q/K column blocks (n0<5120), first-half dims (wn==0)
    if (wn == 0 && n0 < 5120){
      #pragma unroll
      for (int i = 0; i < 4; i++)
        #pragma unroll
        for (int r = 0; r < 4; r++){
          const int row = m0 + wm * 64 + i * 16 + g * 4 + r;
          #pragma unroll
          for (int j = 0; j < 2; j++){
            const int d = j * 16 + ln;               // 0..31, partner d+32
            float c  = cosv[row * 64 + d];
            float sn = sinv[row * 64 + d];
            float x0 = acc[i][j][r], x1 = acc[i][j + 2][r];
            acc[i][j][r]     = x0 * c - x1 * sn;
            acc[i][j + 2][r] = x1 * c + x0 * sn;
          }
        }
    }
    // fold attention scale into Q so attn skips the per-score multiply
    if (n0 < 4096){
      #pragma unroll
      for (int i = 0; i < 4; i++)
        #pragma unroll
        for (int j = 0; j < 4; j++)
          #pragma unroll
          for (int r = 0; r < 4; r++) acc[i][j][r] *= ATT_SCALE;
    }
  }
  // epilogue: C/D layout col = lane&15, row = (lane>>4)*4 + reg  [m89]
  #pragma unroll
  for (int i = 0; i < 4; i++)
    #pragma unroll
    for (int j = 0; j < 4; j++)
      #pragma unroll
      for (int r = 0; r < 4; r++){
        int row = m0 + wm * 64 + i * 16 + g * 4 + r;
        int col = n0 + wn * 64 + j * 16 + ln;
        if (OUT_BF16) ((u16*)Cv)[(size_t)row * N + col] = f2bf(acc[i][j][r]);
        else          ((float*)Cv)[(size_t)row * N + col] = acc[i][j][r];
      }
}

// ---------------- V transpose: VT[kvh][vd][s] from packed QKV -------------
__global__ void vtrans_kernel(const u16* __restrict__ QKV, u16* __restrict__ VT){
  int idx = blockIdx.x * 256 + threadIdx.x;
  if (idx >= NKVH * HD * S_LEN) return;
  int s   = idx & (S_LEN - 1);
  int vd  = (idx >> 11) & (HD - 1);
  int kvh = idx >> 18;
  VT[idx] = QKV[(size_t)s * QKVST + 5120 + kvh * HD + vd];
}

// ---------------- causal flash attention with sink, GQA 4:1 ----------------
// 256 blocks (1/CU), 4 waves, 32 q-rows/wave. Each block processes a PAIR of
// q-stripes {15-p, p} -> uniform 17 K-tiles/block (KVBLK=128): perfectly
// balanced grid (R5/R6's 512-block grid idled 47% on the causal imbalance).
// K/V double-buffered (128KB) + P (16KB) = 144KB LDS. Prefetch pipelines
// across the stripe seam. l via register ones-B-frag MFMA. Defer-max (T13).
// Q pre-scaled. XCD-aligned kvh (b&7).
__global__ __launch_bounds__(256, 1)
void attn_kernel(const u16* __restrict__ QKV, const u16* __restrict__ VT,
                 const float* __restrict__ sinkb, u16* __restrict__ AO){
  __shared__ __align__(16) u16 Ks[2][128 * 128];
  __shared__ __align__(16) u16 Vs[2][128 * 128];
  __shared__ __align__(16) u16 Ps[4][16 * 128];
  const int b   = blockIdx.x;
  const int kvh = b & 7;                 // XCD round-robin -> kvh per XCD
  const int h   = kvh * 4 + ((b >> 3) & 3);
  const int p   = b >> 5;                // 0..7: stripe pair {15-p, p}
  const int a   = 15 - p;
  const int tid = threadIdx.x;
  const int w = tid >> 6, lane = tid & 63;
  const int g = lane >> 4, ln = lane & 15;

  const u16* Kbase = QKV + 4096 + kvh * HD;             // + row*QKVST
  const u16* Vbase = VT + (size_t)kvh * HD * S_LEN;     // + vd*S_LEN + k

  auto stage = [&](int buf, int k0){
    #pragma unroll
    for (int q = 0; q < 8; q++){
      int idx = q * 256 + tid;                 // 0..2047, 16B chunks
      int r = idx >> 4, c16 = idx & 15;
      gload_lds16(Kbase + (size_t)(k0 + r) * QKVST + ((c16 ^ (r & 7)) * 8), &Ks[buf][idx * 8]);
    }
    #pragma unroll
    for (int q = 0; q < 8; q++){
      int idx = q * 256 + tid;
      int vd = idx >> 4, c16 = idx & 15;
      gload_lds16(Vbase + (size_t)vd * S_LEN + k0 + ((c16 ^ (vd & 7)) * 8), &Vs[buf][idx * 8]);
    }
  };

  // register ones-B-frag for l accumulation: B[k][0] = 1 (lanes ln==0)
  u16x8 ob;
  #pragma unroll
  for (int j = 0; j < 8; j++) ob[j] = (ln == 0) ? (u16)0x3F80 : (u16)0;
  const bf16x8 onesf = __builtin_bit_cast(bf16x8, ob);
  const float sb = sinkb[h];

  bf16x8 qf[2][4];
  f32x4 O[2][8];
  f32x4 L[2];
  float m_r[2][4];

  auto load_q = [&](int qw){
    #pragma unroll
    for (int qh = 0; qh < 2; qh++){
      const u16* qrow = QKV + (size_t)(qw + qh * 16 + ln) * QKVST + h * HD;
      #pragma unroll
      for (int t = 0; t < 4; t++) qf[qh][t] = *(const bf16x8*)(qrow + t * 32 + g * 8);
    }
    #pragma unroll
    for (int qh = 0; qh < 2; qh++){
      #pragma unroll
      for (int fn = 0; fn < 8; fn++) O[qh][fn] = f32x4{0.f, 0.f, 0.f, 0.f};
      L[qh] = f32x4{0.f, 0.f, 0.f, 0.f};
      #pragma unroll
      for (int r = 0; r < 4; r++) m_r[qh][r] = -3.0e38f;
    }
  };

  auto do_tile = [&](int cur, int k0, int qw){
    const int nf0 = min(8, ((qw + 15 - k0) >> 4) + 1);   // active frags, qh=0
    const int nf1 = min(8, ((qw + 31 - k0) >> 4) + 1);   // active frags, qh=1
    const bool diag = (k0 + 127 > qw);                   // last tile of stripe
    const u16* Kc = Ks[cur];
    f32x4 sc[2][8] = {};
    // QK^T: frag f covers keys k0+f*16..+15; skip frags beyond causal bound
    __builtin_amdgcn_s_setprio(1);
    #pragma unroll
    for (int f = 0; f < 8; f++){
      if (f < nf1){
        const int krow = f * 16 + ln;
        const bool both = (f < nf0);
        #pragma unroll
        for (int t = 0; t < 4; t++){
          bf16x8 kf = *(const bf16x8*)&Kc[krow * 128 + ((t * 32 + g * 8) ^ ((ln & 7) << 3))];
          sc[1][f] = __builtin_amdgcn_mfma_f32_16x16x32_bf16(qf[1][t], kf, sc[1][f], 0, 0, 0);
          if (both) sc[0][f] = __builtin_amdgcn_mfma_f32_16x16x32_bf16(qf[0][t], kf, sc[0][f], 0, 0, 0);
        }
      }
    }
    __builtin_amdgcn_s_setprio(0);
    // causal mask in place (diag tile only)
    if (diag){
      #pragma unroll
      for (int qh = 0; qh < 2; qh++){
        const int nf = qh ? nf1 : nf0;
        #pragma unroll
        for (int f = 0; f < 8; f++)
          if (f < nf)
            #pragma unroll
            for (int r = 0; r < 4; r++)
              if (k0 + f * 16 + ln > qw + qh * 16 + g * 4 + r) sc[qh][f][r] = -1e30f;
      }
    }
    // per-row tile max over active frags
    float mx[2][4];
    #pragma unroll
    for (int qh = 0; qh < 2; qh++){
      const int nf = qh ? nf1 : nf0;
      #pragma unroll
      for (int r = 0; r < 4; r++){
        float t = -1e30f;
        #pragma unroll
        for (int f = 0; f < 8; f++) if (f < nf) t = fmaxf(t, sc[qh][f][r]);
        #pragma unroll
        for (int d = 1; d < 16; d <<= 1) t = fmaxf(t, __shfl_xor(t, d));
        mx[qh][r] = t;
      }
    }
    // defer-max: only rescale when some row grew past THR
    int ok = 1;
    #pragma unroll
    for (int qh = 0; qh < 2; qh++)
      #pragma unroll
      for (int r = 0; r < 4; r++) ok &= (mx[qh][r] <= m_r[qh][r] + RESCALE_THR);
    if (!__all(ok)){
      #pragma unroll
      for (int qh = 0; qh < 2; qh++){
        float sf_[4];
        #pragma unroll
        for (int r = 0; r < 4; r++){
          float mn = fmaxf(m_r[qh][r], mx[qh][r]);
          sf_[r] = __expf(m_r[qh][r] - mn);
          m_r[qh][r] = mn;
        }
        #pragma unroll
        for (int fn = 0; fn < 8; fn++)
          #pragma unroll
          for (int r = 0; r < 4; r++) O[qh][fn][r] *= sf_[r];
        #pragma unroll
        for (int r = 0; r < 4; r++) L[qh][r] *= sf_[r];
      }
    }
    // P = exp(s - m) -> LDS (per q-half; wave-local LDS ops are in-order)
    u16* Pw = Ps[w];
    bf16x8 pa[2][4];
    #pragma unroll
    for (int qh = 0; qh < 2; qh++){
      const int nf = qh ? nf1 : nf0;
      #pragma unroll
      for (int r = 0; r < 4; r++){
        const int row = g * 4 + r;
        #pragma unroll
        for (int f = 0; f < 8; f++){
          float pp = (f < nf) ? __expf(sc[qh][f][r] - m_r[qh][r]) : 0.f;
          Pw[row * 128 + ((f * 16 + ln) ^ ((row & 7) << 3))] = f2bf(pp);
        }
      }
      #pragma unroll
      for (int hf = 0; hf < 4; hf++)
        pa[qh][hf] = *(const bf16x8*)&Pw[ln * 128 + ((hf * 32 + g * 8) ^ ((ln & 7) << 3))];
    }
    // PV: 32 V-frag reads serve both q-halves; l via register ones-frag
    const u16* Vc = Vs[cur];
    __builtin_amdgcn_s_setprio(1);
    #pragma unroll
    for (int fn = 0; fn < 8; fn++){
      const int vr = fn * 16 + ln;
      #pragma unroll
      for (int hf = 0; hf < 4; hf++){
        bf16x8 vf = *(const bf16x8*)&Vc[vr * 128 + ((hf * 32 + g * 8) ^ ((ln & 7) << 3))];
        O[0][fn] = __builtin_amdgcn_mfma_f32_16x16x32_bf16(pa[0][hf], vf, O[0][fn], 0, 0, 0);
        O[1][fn] = __builtin_amdgcn_mfma_f32_16x16x32_bf16(pa[1][hf], vf, O[1][fn], 0, 0, 0);
      }
    }
    #pragma unroll
    for (int qh = 0; qh < 2; qh++)
      #pragma unroll
      for (int hf = 0; hf < 4; hf++)
        L[qh] = __builtin_amdgcn_mfma_f32_16x16x32_bf16(pa[qh][hf], onesf, L[qh], 0, 0, 0);
    __builtin_amdgcn_s_setprio(0);
  };

  auto finish = [&](int qw){
    #pragma unroll
    for (int qh = 0; qh < 2; qh++)
      #pragma unroll
      for (int r = 0; r < 4; r++){
        float l = __shfl(L[qh][r], lane & 48);
        float mt = fmaxf(m_r[qh][r], sb);
        float lt = l * __expf(m_r[qh][r] - mt) + __expf(sb - mt);
        float osc = __expf(m_r[qh][r] - mt) / lt;
        #pragma unroll
        for (int fn = 0; fn < 8; fn++)
          AO[(size_t)(qw + qh * 16 + g * 4 + r) * AOST + h * HD + fn * 16 + ln] = f2bf(O[qh][fn][r] * osc);
      }
  };

  // ---- segment 0: long stripe qt = a (tiles 0..a) ----
  const int qw_a = a * 128 + w * 32;
  const int qw_b = p * 128 + w * 32;
  stage(0, 0);
  __syncthreads();                       // implicit vmcnt(0): tile 0 ready
  int cur = 0;
  load_q(qw_a);
  for (int kt = 0; kt <= a; kt++){
    stage(cur ^ 1, (kt < a) ? (kt + 1) * 128 : 0);   // seam: prefetch seg1 tile 0
    do_tile(cur, kt * 128, qw_a);
    __syncthreads();
    cur ^= 1;
  }
  finish(qw_a);
  // ---- segment 1: short stripe qt = p (tiles 0..p) ----
  load_q(qw_b);
  for (int kt = 0; kt <= p; kt++){
    if (kt < p) stage(cur ^ 1, (kt + 1) * 128);
    do_tile(cur, kt * 128, qw_b);
    __syncthreads();
    cur ^= 1;
  }
  finish(qw_b);
}

// ---------------- host-side launch ----------------
extern "C" void kernel_launch(void* const* d_in, const int* in_sizes, int n_in,
                              void* d_out, int out_size, void* d_ws, size_t ws_size,
                              hipStream_t stream){
  (void)in_sizes; (void)n_in; (void)out_size; (void)ws_size;
  const float* hs    = (const float*)d_in[0];
  const float* cosv  = (const float*)d_in[1];
  const float* sinv  = (const float*)d_in[2];
  /* d_in[3] attention_mask: pure causal triu(NEG,1) - implemented directly */
  const float* Wq    = (const float*)d_in[4];
  const float* Wk    = (const float*)d_in[5];
  const float* Wv    = (const float*)d_in[6];
  const float* Wo    = (const float*)d_in[7];
  const float* sinkb = (const float*)d_in[8];
  float* out = (float*)d_out;

  char* ws = (char*)d_ws;
  u16* XB    = (u16*)(ws);                  //  8,388,608  X bf16 [2048][2048]
  u16* WQKVB = (u16*)(ws + 8388608);        // 25,165,824  Wqkv bf16 [6144][2048]
  u16* WOB   = (u16*)(ws + 33554432);       // 16,777,216  Wo bf16 [2048][4096]
  u16* QKV   = (u16*)(ws + 50331648);       // 25,165,824  QKV bf16 [2048][6144]
  u16* VT    = (u16*)(ws + 75497472);       //  4,194,304  V^T bf16 [8][128][2048]
  u16* AO    = (u16*)(ws + 79691776);       // 16,777,216  attn out bf16 [2048][4096]

  // single fused convert: hs|Wq|Wk|Wv|Wo -> XB|WQKVB|WOB (contiguous in ws)
  cvt_all_kernel<<<24576, 256, 0, stream>>>((const f32x4*)hs, (const f32x4*)Wq,
                                            (const f32x4*)Wk, (const f32x4*)Wv,
                                            (const f32x4*)Wo, (u16x4*)ws);

  // fused QKV projection + RoPE + Q-scale epilogue: [2048][6144]
  gemm_bt_kernel<1, 1><<<dim3(48, 16), 256, 0, stream>>>(XB, WQKVB, QKV, 2048, 6144, 2048, cosv, sinv);

  // V transpose (V region carries no rope)
  vtrans_kernel<<<8192, 256, 0, stream>>>(QKV, VT);

  // attention: 256 balanced blocks (stripe pairs), XCD-aligned kvh
  attn_kernel<<<dim3(256), 256, 0, stream>>>(QKV, VT, sinkb, AO);

  // output projection (f32 out)
  gemm_bt_kernel<0, 0><<<dim3(16, 16), 256, 0, stream>>>(AO, WOB, out, 2048, 2048, 4096, nullptr, nullptr);
}

// Round 8
// 269.159 us; speedup vs baseline: 1.0494x; 1.0494x over previous
//
#include <hip/hip_runtime.h>

typedef unsigned short u16;
typedef unsigned int   u32;
typedef __bf16  bf16x8 __attribute__((ext_vector_type(8)));
typedef float   f32x4  __attribute__((ext_vector_type(4)));
typedef u16     u16x4  __attribute__((ext_vector_type(4)));
typedef u16     u16x8  __attribute__((ext_vector_type(8)));

#define S_LEN 2048
#define NH 32
#define NKVH 8
#define HD 128
#define QKVST 6144          /* packed QKV row stride  */
#define AOST  4096          /* attn-out row stride    */
#define ATT_SCALE 0.08838834764831845f
#define LOG2E 1.4426950408889634f
/* Q is pre-scaled by ATT_SCALE*LOG2E -> scores are log2-domain logits */
#define QSC2 (ATT_SCALE * LOG2E)
#define RESCALE_THR2 11.5f   /* = 8 nats in log2 units; P bounded by 2^11.5 */

__device__ __forceinline__ u16 f2bf(float f){
  u32 u = __builtin_bit_cast(u32, f);
  u += 0x7FFFu + ((u >> 16) & 1u);
  return (u16)(u >> 16);
}
__device__ __forceinline__ float bf2f(u16 h){
  u32 u = ((u32)h) << 16;
  return __builtin_bit_cast(float, u);
}
// async global->LDS, 16B per lane. Dest must be wave-uniform base + lane*16.
__device__ __forceinline__ void gload_lds16(const u16* g, u16* l){
  __builtin_amdgcn_global_load_lds(
      (const __attribute__((address_space(1))) void*)g,
      (__attribute__((address_space(3))) void*)l, 16, 0, 0);
}

// ------------- fused f32 -> bf16 convert of ALL inputs (one launch) --------
// ws layout is contiguous & source-ordered: XB | Wq | Wk | Wv | Wo
__global__ void cvt_all_kernel(const f32x4* __restrict__ hs, const f32x4* __restrict__ wq,
                               const f32x4* __restrict__ wk, const f32x4* __restrict__ wv,
                               const f32x4* __restrict__ wo, u16x4* __restrict__ out){
  int i = blockIdx.x * 256 + threadIdx.x;          // 0 .. 6291455
  const f32x4* src; int off;
  if      (i < 1048576){ src = hs; off = i; }
  else if (i < 3145728){ src = wq; off = i - 1048576; }
  else if (i < 3670016){ src = wk; off = i - 3145728; }
  else if (i < 4194304){ src = wv; off = i - 3670016; }
  else                 { src = wo; off = i - 4194304; }
  f32x4 v = src[off];
  u16x4 o;
  o[0] = f2bf(v[0]); o[1] = f2bf(v[1]); o[2] = f2bf(v[2]); o[3] = f2bf(v[3]);
  out[i] = o;
}

// ---------------- GEMM: C[M][N] = X[M][K] @ W[N][K]^T (bf16 in, f32 acc) ----
// 128x128 tile, BK=64 (2x [128][32] sub-tiles), double-buffered prefetch.
// ROPE=1 fuses partial RoPE (Q+K cols, n0<5120) and QSC2 (Q cols, n0<4096).
template<int OUT_BF16, int ROPE>
__global__ __launch_bounds__(256, 2)
void gemm_bt_kernel(const u16* __restrict__ X, const u16* __restrict__ W,
                    void* __restrict__ Cv, int M, int N, int K,
                    const float* __restrict__ cosv, const float* __restrict__ sinv){
  __shared__ __align__(16) u16 As[2][2][128 * 32];
  __shared__ __align__(16) u16 Bs[2][2][128 * 32];
  const int m0 = blockIdx.y * 128, n0 = blockIdx.x * 128;
  const int tid = threadIdx.x;
  const int wave = tid >> 6, lane = tid & 63;
  const int wm = wave >> 1, wn = wave & 1;
  const int g = lane >> 4, ln = lane & 15;
  const int r0 = tid >> 2;            // rows 0..63 (tid*16B == linear LDS dest)
  const int cc = (tid & 3) * 8;       // bf16 col within sub-tile BK=32
  f32x4 acc[4][4] = {};
  const u16* xa0 = X + (size_t)(m0 + r0) * K + cc;
  const u16* xa1 = X + (size_t)(m0 + r0 + 64) * K + cc;
  const u16* wb0 = W + (size_t)(n0 + r0) * K + cc;
  const u16* wb1 = W + (size_t)(n0 + r0 + 64) * K + cc;

  auto stage = [&](int buf, int k0){
    #pragma unroll
    for (int s = 0; s < 2; s++){
      const int kc = k0 + s * 32;
      gload_lds16(xa0 + kc, &As[buf][s][tid * 8]);
      gload_lds16(xa1 + kc, &As[buf][s][2048 + tid * 8]);
      gload_lds16(wb0 + kc, &Bs[buf][s][tid * 8]);
      gload_lds16(wb1 + kc, &Bs[buf][s][2048 + tid * 8]);
    }
  };

  stage(0, 0);
  __syncthreads();                       // implicit vmcnt(0): tile 0 ready
  int cur = 0;
  for (int k0 = 0; k0 < K; k0 += 64){
    if (k0 + 64 < K) stage(cur ^ 1, k0 + 64);   // prefetch overlaps compute
    #pragma unroll
    for (int s = 0; s < 2; s++){
      bf16x8 a[4], b[4];
      #pragma unroll
      for (int f = 0; f < 4; f++) a[f] = *(const bf16x8*)&As[cur][s][(wm * 64 + f * 16 + ln) * 32 + g * 8];
      #pragma unroll
      for (int f = 0; f < 4; f++) b[f] = *(const bf16x8*)&Bs[cur][s][(wn * 64 + f * 16 + ln) * 32 + g * 8];
      __builtin_amdgcn_s_setprio(1);
      #pragma unroll
      for (int i = 0; i < 4; i++)
        #pragma unroll
        for (int j = 0; j < 4; j++)
          acc[i][j] = __builtin_amdgcn_mfma_f32_16x16x32_bf16(a[i], b[j], acc[i][j], 0, 0, 0);
      __builtin_amdgcn_s_setprio(0);
    }
    __syncthreads();   // ONE barrier/tile: drains prefetch vmcnt + guards reuse
    cur ^= 1;
  }
  if (ROPE){
    // fused partial RoPE: Q/K column blocks (n0<5120), first-half dims (wn==0)
    if (wn == 0 && n0 < 5120){
      #pragma unroll
      for (int i = 0; i < 4; i++)
        #pragma unroll
        for (int r = 0; r < 4; r++){
          const int row = m0 + wm * 64 + i * 16 + g * 4 + r;
          #pragma unroll
          for (int j = 0; j < 2; j++){
            const int d = j * 16 + ln;               // 0..31, partner d+32
            float c  = cosv[row * 64 + d];
            float sn = sinv[row * 64 + d];
            float x0 = acc[i][j][r], x1 = acc[i][j + 2][r];
            acc[i][j][r]     = x0 * c - x1 * sn;
            acc[i][j + 2][r] = x1 * c + x0 * sn;
          }
        }
    }
    // fold attention scale * log2(e) into Q: attn works in exp2 domain
    if (n0 < 4096){
      #pragma unroll
      for (int i = 0; i < 4; i++)
        #pragma unroll
        for (int j = 0; j < 4; j++)
          #pragma unroll
          for (int r = 0; r < 4; r++) acc[i][j][r] *= QSC2;
    }
  }
  // epilogue: C/D layout col = lane&15, row = (lane>>4)*4 + reg  [m89]
  #pragma unroll
  for (int i = 0; i < 4; i++)
    #pragma unroll
    for (int j = 0; j < 4; j++)
      #pragma unroll
      for (int r = 0; r < 4; r++){
        int row = m0 + wm * 64 + i * 16 + g * 4 + r;
        int col = n0 + wn * 64 + j * 16 + ln;
        if (OUT_BF16) ((u16*)Cv)[(size_t)row * N + col] = f2bf(acc[i][j][r]);
        else          ((float*)Cv)[(size_t)row * N + col] = acc[i][j][r];
      }
}

// ---------------- V transpose: VT[kvh][vd][s] from packed QKV -------------
__global__ void vtrans_kernel(const u16* __restrict__ QKV, u16* __restrict__ VT){
  int idx = blockIdx.x * 256 + threadIdx.x;
  if (idx >= NKVH * HD * S_LEN) return;
  int s   = idx & (S_LEN - 1);
  int vd  = (idx >> 11) & (HD - 1);
  int kvh = idx >> 18;
  VT[idx] = QKV[(size_t)s * QKVST + 5120 + kvh * HD + vd];
}

// ---------------- causal flash attention with sink, GQA 4:1 ----------------
// R4-measured-optimum geometry: 4 waves/block, 16 q-rows/wave, 1024 blocks,
// KVBLK=64, double-buffered LDS prefetch, ONE barrier/tile, 72KB LDS ->
// 2 blocks/CU (8 waves/CU TLP — R5/R6/R7 showed bigger per-wave tiles lose
// more to latency exposure than they save in LDS traffic).
// Deltas vs R4: l via REGISTER ones-B-frag MFMA (-2 LDS reads/tile, -4KB),
// per-wave nf guard skips masked frags on diag tile, exp2-domain softmax
// (Q pre-scaled by ATT_SCALE*log2e). XCD-aligned kvh (b&7), LPT order.
__global__ __launch_bounds__(256, 2)
void attn_kernel(const u16* __restrict__ QKV, const u16* __restrict__ VT,
                 const float* __restrict__ sinkb, u16* __restrict__ AO){
  __shared__ __align__(16) u16 Ks[2][64 * 128];
  __shared__ __align__(16) u16 Vs[2][128 * 64];
  __shared__ __align__(16) u16 Ps[4][16 * 64];
  const int b   = blockIdx.x;
  const int kvh = b & 7;                 // XCD round-robin -> kvh per XCD
  const int h   = kvh * 4 + ((b >> 3) & 3);
  const int qt  = 31 - (b >> 5);         // longest blocks first
  const int tid = threadIdx.x;
  const int w = tid >> 6, lane = tid & 63;
  const int g = lane >> 4, ln = lane & 15;
  const int q0 = qt * 64;
  const int qw = q0 + w * 16;

  const u16* Kbase = QKV + 4096 + kvh * HD;             // + row*QKVST
  const u16* Vbase = VT + (size_t)kvh * HD * S_LEN;     // + vd*S_LEN + k

  auto stage = [&](int buf, int kt){
    const int k0 = kt * 64;
    #pragma unroll
    for (int p = 0; p < 4; p++){
      int idx = p * 256 + tid;
      int r = idx >> 4, c16 = idx & 15;
      gload_lds16(Kbase + (size_t)(k0 + r) * QKVST + ((c16 ^ (r & 7)) * 8), &Ks[buf][idx * 8]);
    }
    #pragma unroll
    for (int p = 0; p < 4; p++){
      int idx = p * 256 + tid;
      int vd = idx >> 3, c8 = idx & 7;
      gload_lds16(Vbase + (size_t)vd * S_LEN + k0 + ((c8 ^ (vd & 7)) * 8), &Vs[buf][idx * 8]);
    }
  };

  // register ones-B-frag for l accumulation: B[k][0] = 1 (lanes ln==0)
  u16x8 ob;
  #pragma unroll
  for (int j = 0; j < 8; j++) ob[j] = (ln == 0) ? (u16)0x3F80 : (u16)0;
  const bf16x8 onesf = __builtin_bit_cast(bf16x8, ob);

  // Q A-frags (pre-scaled by ATT_SCALE*log2e): row = ln, k = t*32 + g*8 + j
  bf16x8 qf[4];
  const u16* qrow = QKV + (size_t)(qw + ln) * QKVST + h * HD;
  #pragma unroll
  for (int t = 0; t < 4; t++) qf[t] = *(const bf16x8*)(qrow + t * 32 + g * 8);

  f32x4 O[8] = {};
  f32x4 L = {};
  float m_r[4];
  #pragma unroll
  for (int r = 0; r < 4; r++) m_r[r] = -3.0e38f;

  const int nkt = qt + 1;
  stage(0, 0);
  __syncthreads();
  int cur = 0;

  for (int kt = 0; kt < nkt; kt++){
    const int k0 = kt * 64;
    if (kt + 1 < nkt) stage(cur ^ 1, kt + 1);   // prefetch overlaps compute

    // active 16-key frags for this wave (uniform): last tile may mask some
    const int nf = min(4, ((qw + 15 - k0) >> 4) + 1);

    // QK^T: up to 16 MFMAs -> sc[f]; q row = g*4+r, key = k0 + f*16 + ln
    const u16* Kc = Ks[cur];
    f32x4 sc[4] = {};
    __builtin_amdgcn_s_setprio(1);
    #pragma unroll
    for (int f = 0; f < 4; f++){
      if (f < nf){
        const int krow = f * 16 + ln;
        #pragma unroll
        for (int t = 0; t < 4; t++){
          bf16x8 kf = *(const bf16x8*)&Kc[krow * 128 + ((t * 32 + g * 8) ^ ((ln & 7) << 3))];
          sc[f] = __builtin_amdgcn_mfma_f32_16x16x32_bf16(qf[t], kf, sc[f], 0, 0, 0);
        }
      }
    }
    __builtin_amdgcn_s_setprio(0);

    // causal mask (diag frag only) — log2-domain logits
    const bool needmask = (k0 + 63 > qw);
    if (needmask){
      #pragma unroll
      for (int f = 0; f < 4; f++)
        if (f < nf)
          #pragma unroll
          for (int r = 0; r < 4; r++)
            if (k0 + f * 16 + ln > qw + g * 4 + r) sc[f][r] = -1e30f;
    }
    // per-row tile max over active frags
    float mx[4];
    #pragma unroll
    for (int r = 0; r < 4; r++){
      float t = -1e30f;
      #pragma unroll
      for (int f = 0; f < 4; f++) if (f < nf) t = fmaxf(t, sc[f][r]);
      #pragma unroll
      for (int d = 1; d < 16; d <<= 1) t = fmaxf(t, __shfl_xor(t, d));
      mx[r] = t;
    }
    // defer-max: only rescale when some row grew past THR (log2 units)
    int ok = (mx[0] <= m_r[0] + RESCALE_THR2) & (mx[1] <= m_r[1] + RESCALE_THR2)
           & (mx[2] <= m_r[2] + RESCALE_THR2) & (mx[3] <= m_r[3] + RESCALE_THR2);
    if (!__all(ok)){
      float sf_[4];
      #pragma unroll
      for (int r = 0; r < 4; r++){
        float mn = fmaxf(m_r[r], mx[r]);
        sf_[r] = exp2f(m_r[r] - mn);
        m_r[r] = mn;
      }
      #pragma unroll
      for (int fn = 0; fn < 8; fn++)
        #pragma unroll
        for (int r = 0; r < 4; r++) O[fn][r] *= sf_[r];
      #pragma unroll
      for (int r = 0; r < 4; r++) L[r] *= sf_[r];
    }
    // P = exp2(s - m), store bf16 (swizzled) for PV A-frag; 0 for masked frags
    u16* Pw = Ps[w];
    #pragma unroll
    for (int r = 0; r < 4; r++){
      const int row = g * 4 + r;
      #pragma unroll
      for (int f = 0; f < 4; f++){
        u16 pb = (f < nf) ? f2bf(exp2f(sc[f][r] - m_r[r])) : (u16)0;
        Pw[row * 64 + ((f * 16 + ln) ^ ((row & 7) << 3))] = pb;
      }
    }
    // PV: P A-frag row = ln, k = hf*32 + g*8 + j (wave-local LDS, in-order)
    const u16* Vc = Vs[cur];
    bf16x8 pa0 = *(const bf16x8*)&Pw[ln * 64 + ((g * 8)      ^ ((ln & 7) << 3))];
    bf16x8 pa1 = *(const bf16x8*)&Pw[ln * 64 + ((32 + g * 8) ^ ((ln & 7) << 3))];
    __builtin_amdgcn_s_setprio(1);
    #pragma unroll
    for (int fn = 0; fn < 8; fn++){
      const int vr = fn * 16 + ln;
      bf16x8 v0 = *(const bf16x8*)&Vc[vr * 64 + ((g * 8)      ^ ((ln & 7) << 3))];
      bf16x8 v1 = *(const bf16x8*)&Vc[vr * 64 + ((32 + g * 8) ^ ((ln & 7) << 3))];
      O[fn] = __builtin_amdgcn_mfma_f32_16x16x32_bf16(pa0, v0, O[fn], 0, 0, 0);
      O[fn] = __builtin_amdgcn_mfma_f32_16x16x32_bf16(pa1, v1, O[fn], 0, 0, 0);
    }
    L = __builtin_amdgcn_mfma_f32_16x16x32_bf16(pa0, onesf, L, 0, 0, 0);
    L = __builtin_amdgcn_mfma_f32_16x16x32_bf16(pa1, onesf, L, 0, 0, 0);
    __builtin_amdgcn_s_setprio(0);

    __syncthreads();   // ONE barrier/tile: drains prefetch vmcnt + guards reuse
    cur ^= 1;
  }
  // l lives in L[r] of lanes ln==0; broadcast within 16-lane group, then
  // fold sink into the denominator (log2 domain: sb' = sb*log2e)
  float sb2 = sinkb[h] * LOG2E;
  #pragma unroll
  for (int r = 0; r < 4; r++){
    float l = __shfl(L[r], lane & 48);
    float mt = fmaxf(m_r[r], sb2);
    float lt = l * exp2f(m_r[r] - mt) + exp2f(sb2 - mt);
    float osc = exp2f(m_r[r] - mt) / lt;
    #pragma unroll
    for (int fn = 0; fn < 8; fn++)
      AO[(size_t)(qw + g * 4 + r) * AOST + h * HD + fn * 16 + ln] = f2bf(O[fn][r] * osc);
  }
}

// ---------------- host-side launch ----------------
extern "C" void kernel_launch(void* const* d_in, const int* in_sizes, int n_in,
                              void* d_out, int out_size, void* d_ws, size_t ws_size,
                              hipStream_t stream){
  (void)in_sizes; (void)n_in; (void)out_size; (void)ws_size;
  const float* hs    = (const float*)d_in[0];
  const float* cosv  = (const float*)d_in[1];
  const float* sinv  = (const float*)d_in[2];
  /* d_in[3] attention_mask: pure causal triu(NEG,1) - implemented directly */
  const float* Wq    = (const float*)d_in[4];
  const float* Wk    = (const float*)d_in[5];
  const float* Wv    = (const float*)d_in[6];
  const float* Wo    = (const float*)d_in[7];
  const float* sinkb = (const float*)d_in[8];
  float* out = (float*)d_out;

  char* ws = (char*)d_ws;
  u16* XB    = (u16*)(ws);                  //  8,388,608  X bf16 [2048][2048]
  u16* WQKVB = (u16*)(ws + 8388608);        // 25,165,824  Wqkv bf16 [6144][2048]
  u16* WOB   = (u16*)(ws + 33554432);       // 16,777,216  Wo bf16 [2048][4096]
  u16* QKV   = (u16*)(ws + 50331648);       // 25,165,824  QKV bf16 [2048][6144]
  u16* VT    = (u16*)(ws + 75497472);       //  4,194,304  V^T bf16 [8][128][2048]
  u16* AO    = (u16*)(ws + 79691776);       // 16,777,216  attn out bf16 [2048][4096]

  // single fused convert: hs|Wq|Wk|Wv|Wo -> XB|WQKVB|WOB (contiguous in ws)
  cvt_all_kernel<<<24576, 256, 0, stream>>>((const f32x4*)hs, (const f32x4*)Wq,
                                            (const f32x4*)Wk, (const f32x4*)Wv,
                                            (const f32x4*)Wo, (u16x4*)ws);

  // fused QKV projection + RoPE + Q-scale(log2e) epilogue: [2048][6144]
  gemm_bt_kernel<1, 1><<<dim3(48, 16), 256, 0, stream>>>(XB, WQKVB, QKV, 2048, 6144, 2048, cosv, sinv);

  // V transpose (V region carries no rope)
  vtrans_kernel<<<8192, 256, 0, stream>>>(QKV, VT);

  // attention: flat 1024-block grid (64 q-rows/block), XCD-aligned kvh
  attn_kernel<<<dim3(1024), 256, 0, stream>>>(QKV, VT, sinkb, AO);

  // output projection (f32 out)
  gemm_bt_kernel<0, 0><<<dim3(16, 16), 256, 0, stream>>>(AO, WOB, out, 2048, 2048, 4096, nullptr, nullptr);
}

// Round 9
// 242.670 us; speedup vs baseline: 1.1639x; 1.1092x over previous
//
#include <hip/hip_runtime.h>

typedef unsigned short u16;
typedef unsigned int   u32;
typedef __bf16  bf16x8 __attribute__((ext_vector_type(8)));
typedef float   f32x4  __attribute__((ext_vector_type(4)));
typedef u16     u16x4  __attribute__((ext_vector_type(4)));
typedef u16     u16x8  __attribute__((ext_vector_type(8)));

#define S_LEN 2048
#define NH 32
#define NKVH 8
#define HD 128
#define QKVST 6144          /* packed QKV row stride  */
#define AOST  4096          /* attn-out row stride    */
#define ATT_SCALE 0.08838834764831845f
#define LOG2E 1.4426950408889634f
/* Q is pre-scaled by ATT_SCALE*LOG2E -> scores are log2-domain logits */
#define QSC2 (ATT_SCALE * LOG2E)
#define RESCALE_THR2 11.5f   /* = 8 nats in log2 units; P bounded by 2^11.5 */

__device__ __forceinline__ u16 f2bf(float f){
  u32 u = __builtin_bit_cast(u32, f);
  u += 0x7FFFu + ((u >> 16) & 1u);
  return (u16)(u >> 16);
}
__device__ __forceinline__ float bf2f(u16 h){
  u32 u = ((u32)h) << 16;
  return __builtin_bit_cast(float, u);
}
// async global->LDS, 16B per lane. Dest must be wave-uniform base + lane*16.
__device__ __forceinline__ void gload_lds16(const u16* g, u16* l){
  __builtin_amdgcn_global_load_lds(
      (const __attribute__((address_space(1))) void*)g,
      (__attribute__((address_space(3))) void*)l, 16, 0, 0);
}

// ------------- fused f32 -> bf16 convert of ALL inputs (one launch) --------
// ws layout is contiguous & source-ordered: XB | Wq | Wk | Wv | Wo
__global__ void cvt_all_kernel(const f32x4* __restrict__ hs, const f32x4* __restrict__ wq,
                               const f32x4* __restrict__ wk, const f32x4* __restrict__ wv,
                               const f32x4* __restrict__ wo, u16x4* __restrict__ out){
  int i = blockIdx.x * 256 + threadIdx.x;          // 0 .. 6291455
  const f32x4* src; int off;
  if      (i < 1048576){ src = hs; off = i; }
  else if (i < 3145728){ src = wq; off = i - 1048576; }
  else if (i < 3670016){ src = wk; off = i - 3145728; }
  else if (i < 4194304){ src = wv; off = i - 3670016; }
  else                 { src = wo; off = i - 4194304; }
  f32x4 v = src[off];
  u16x4 o;
  o[0] = f2bf(v[0]); o[1] = f2bf(v[1]); o[2] = f2bf(v[2]); o[3] = f2bf(v[3]);
  out[i] = o;
}

// ---------------- GEMM: C[M][N] = X[M][K] @ W[N][K]^T (bf16 in, f32 acc) ----
// 128(M) x BN(N) tile, BK=64 (2x 32-sub-tiles), double-buffered prefetch.
// BN=128: 4 waves 2x2, wave-tile 64x64. BN=64: 4 waves 2x2, wave-tile 64x32
// (for grids that would otherwise land at 1 block/CU, e.g. O-proj 2048x2048).
// ROPE=1 fuses partial RoPE (Q+K cols, n0<5120) and QSC2 (Q cols, n0<4096).
template<int OUT_BF16, int ROPE, int BN>
__global__ __launch_bounds__(256, 2)
void gemm_bt_kernel(const u16* __restrict__ X, const u16* __restrict__ W,
                    void* __restrict__ Cv, int M, int N, int K,
                    const float* __restrict__ cosv, const float* __restrict__ sinv){
  __shared__ __align__(16) u16 As[2][2][128 * 32];
  __shared__ __align__(16) u16 Bs[2][2][BN * 32];
  const int NJ = BN / 32;             // b-frags per wave
  const int m0 = blockIdx.y * 128, n0 = blockIdx.x * BN;
  const int tid = threadIdx.x;
  const int wave = tid >> 6, lane = tid & 63;
  const int wm = wave >> 1, wn = wave & 1;
  const int g = lane >> 4, ln = lane & 15;
  const int r0 = tid >> 2;            // rows 0..63 (tid*16B == linear LDS dest)
  const int cc = (tid & 3) * 8;       // bf16 col within sub-tile BK=32
  f32x4 acc[4][NJ] = {};
  const u16* xa0 = X + (size_t)(m0 + r0) * K + cc;
  const u16* xa1 = X + (size_t)(m0 + r0 + 64) * K + cc;
  const u16* wb0 = W + (size_t)(n0 + r0) * K + cc;
  const u16* wb1 = W + (size_t)(n0 + r0 + (BN == 128 ? 64 : 0)) * K + cc;

  auto stage = [&](int buf, int k0){
    #pragma unroll
    for (int s = 0; s < 2; s++){
      const int kc = k0 + s * 32;
      gload_lds16(xa0 + kc, &As[buf][s][tid * 8]);
      gload_lds16(xa1 + kc, &As[buf][s][2048 + tid * 8]);
      gload_lds16(wb0 + kc, &Bs[buf][s][tid * 8]);
      if (BN == 128) gload_lds16(wb1 + kc, &Bs[buf][s][2048 + tid * 8]);
    }
  };

  stage(0, 0);
  __syncthreads();                       // implicit vmcnt(0): tile 0 ready
  int cur = 0;
  for (int k0 = 0; k0 < K; k0 += 64){
    if (k0 + 64 < K) stage(cur ^ 1, k0 + 64);   // prefetch overlaps compute
    #pragma unroll
    for (int s = 0; s < 2; s++){
      bf16x8 a[4], b[NJ];
      #pragma unroll
      for (int f = 0; f < 4; f++) a[f] = *(const bf16x8*)&As[cur][s][(wm * 64 + f * 16 + ln) * 32 + g * 8];
      #pragma unroll
      for (int f = 0; f < NJ; f++) b[f] = *(const bf16x8*)&Bs[cur][s][(wn * (BN / 2) + f * 16 + ln) * 32 + g * 8];
      __builtin_amdgcn_s_setprio(1);
      #pragma unroll
      for (int i = 0; i < 4; i++)
        #pragma unroll
        for (int j = 0; j < NJ; j++)
          acc[i][j] = __builtin_amdgcn_mfma_f32_16x16x32_bf16(a[i], b[j], acc[i][j], 0, 0, 0);
      __builtin_amdgcn_s_setprio(0);
    }
    __syncthreads();   // ONE barrier/tile: drains prefetch vmcnt + guards reuse
    cur ^= 1;
  }
  if (ROPE && BN == 128){
    // fused partial RoPE: Q/K column blocks (n0<5120), first-half dims (wn==0)
    if (wn == 0 && n0 < 5120){
      #pragma unroll
      for (int i = 0; i < 4; i++)
        #pragma unroll
        for (int r = 0; r < 4; r++){
          const int row = m0 + wm * 64 + i * 16 + g * 4 + r;
          #pragma unroll
          for (int j = 0; j < 2; j++){
            const int d = j * 16 + ln;               // 0..31, partner d+32
            float c  = cosv[row * 64 + d];
            float sn = sinv[row * 64 + d];
            float x0 = acc[i][j][r], x1 = acc[i][j + 2][r];
            acc[i][j][r]     = x0 * c - x1 * sn;
            acc[i][j + 2][r] = x1 * c + x0 * sn;
          }
        }
    }
    // fold attention scale * log2(e) into Q: attn works in exp2 domain
    if (n0 < 4096){
      #pragma unroll
      for (int i = 0; i < 4; i++)
        #pragma unroll
        for (int j = 0; j < 4; j++)
          #pragma unroll
          for (int r = 0; r < 4; r++) acc[i][j][r] *= QSC2;
    }
  }
  // epilogue: C/D layout col = lane&15, row = (lane>>4)*4 + reg  [m89]
  #pragma unroll
  for (int i = 0; i < 4; i++)
    #pragma unroll
    for (int j = 0; j < NJ; j++)
      #pragma unroll
      for (int r = 0; r < 4; r++){
        int row = m0 + wm * 64 + i * 16 + g * 4 + r;
        int col = n0 + wn * (BN / 2) + j * 16 + ln;
        if (OUT_BF16) ((u16*)Cv)[(size_t)row * N + col] = f2bf(acc[i][j][r]);
        else          ((float*)Cv)[(size_t)row * N + col] = acc[i][j][r];
      }
}

// ---------------- V transpose: VT[kvh][vd][s] from packed QKV -------------
__global__ void vtrans_kernel(const u16* __restrict__ QKV, u16* __restrict__ VT){
  int idx = blockIdx.x * 256 + threadIdx.x;
  if (idx >= NKVH * HD * S_LEN) return;
  int s   = idx & (S_LEN - 1);
  int vd  = (idx >> 11) & (HD - 1);
  int kvh = idx >> 18;
  VT[idx] = QKV[(size_t)s * QKVST + 5120 + kvh * HD + vd];
}

// ---------------- causal flash attention with sink, GQA 4:1 ----------------
// R4's measured-optimum kernel, exactly: 4 waves/block, 16 q-rows/wave,
// 1024 blocks, KVBLK=64, dbuf prefetch, ONE barrier/tile, flat unconditional
// QK loop (R8's divergent nf-guard cost ~19us of schedule quality), LDS
// ones-row 9th PV fragment for l. Only provably-free deltas vs R4:
//  - Q pre-scaled by ATT_SCALE*log2e in GEMM (exp2 domain, no per-score mul)
//  - sink folded into init: m_r = sink*log2e, O[8] = 1 at col 0 -> the
//    cumulative defer-rescale product IS the sink term; epilogue = 1/l.
__global__ __launch_bounds__(256, 2)
void attn_kernel(const u16* __restrict__ QKV, const u16* __restrict__ VT,
                 const float* __restrict__ sinkb, u16* __restrict__ AO){
  __shared__ __align__(16) u16 Ks[2][64 * 128];
  __shared__ __align__(16) u16 Vs[2][144 * 64];
  __shared__ __align__(16) u16 Ps[4][16 * 64];
  const int b   = blockIdx.x;
  const int kvh = b & 7;                 // XCD round-robin -> kvh per XCD
  const int h   = kvh * 4 + ((b >> 3) & 3);
  const int qt  = 31 - (b >> 5);         // longest blocks first
  const int tid = threadIdx.x;
  const int w = tid >> 6, lane = tid & 63;
  const int g = lane >> 4, ln = lane & 15;
  const int q0 = qt * 64;
  const int qw = q0 + w * 16;

  const u16* Kbase = QKV + 4096 + kvh * HD;             // + row*QKVST
  const u16* Vbase = VT + (size_t)kvh * HD * S_LEN;     // + vd*S_LEN + k

  auto stage = [&](int buf, int kt){
    const int k0 = kt * 64;
    #pragma unroll
    for (int p = 0; p < 4; p++){
      int idx = p * 256 + tid;
      int r = idx >> 4, c16 = idx & 15;
      gload_lds16(Kbase + (size_t)(k0 + r) * QKVST + ((c16 ^ (r & 7)) * 8), &Ks[buf][idx * 8]);
    }
    #pragma unroll
    for (int p = 0; p < 4; p++){
      int idx = p * 256 + tid;
      int vd = idx >> 3, c8 = idx & 7;
      gload_lds16(Vbase + (size_t)vd * S_LEN + k0 + ((c8 ^ (vd & 7)) * 8), &Vs[buf][idx * 8]);
    }
  };

  // ones-rows for l-accumulation: row 128 = 1.0, rows 129..143 = 0
  for (int i = tid; i < 16 * 64; i += 256){
    u16 v = (i < 64) ? (u16)0x3F80 : (u16)0;
    Vs[0][128 * 64 + i] = v;
    Vs[1][128 * 64 + i] = v;
  }

  // Q A-frags (pre-scaled by ATT_SCALE*log2e): row = ln, k = t*32 + g*8 + j
  bf16x8 qf[4];
  const u16* qrow = QKV + (size_t)(qw + ln) * QKVST + h * HD;
  #pragma unroll
  for (int t = 0; t < 4; t++) qf[t] = *(const bf16x8*)(qrow + t * 32 + g * 8);

  // sink folded into init: m = sb2; O[8] (l-accum) starts at 1 in col 0.
  const float sb2 = sinkb[h] * LOG2E;
  f32x4 O[9] = {};
  O[8][0] = O[8][1] = O[8][2] = O[8][3] = (ln == 0) ? 1.f : 0.f;
  float m_r[4];
  #pragma unroll
  for (int r = 0; r < 4; r++) m_r[r] = sb2;

  const int nkt = qt + 1;
  stage(0, 0);
  __syncthreads();
  int cur = 0;

  for (int kt = 0; kt < nkt; kt++){
    const int k0 = kt * 64;
    if (kt + 1 < nkt) stage(cur ^ 1, kt + 1);   // prefetch overlaps compute

    // QK^T: 16 MFMAs, flat/unconditional -> sc[f]; key = k0 + f*16 + ln
    const u16* Kc = Ks[cur];
    f32x4 sc[4] = {};
    __builtin_amdgcn_s_setprio(1);
    #pragma unroll
    for (int f = 0; f < 4; f++){
      const int krow = f * 16 + ln;
      #pragma unroll
      for (int t = 0; t < 4; t++){
        bf16x8 kf = *(const bf16x8*)&Kc[krow * 128 + ((t * 32 + g * 8) ^ ((ln & 7) << 3))];
        sc[f] = __builtin_amdgcn_mfma_f32_16x16x32_bf16(qf[t], kf, sc[f], 0, 0, 0);
      }
    }
    __builtin_amdgcn_s_setprio(0);

    // causal mask (diag tile only) — log2-domain logits
    const bool diag = (kt == qt);
    if (diag){
      #pragma unroll
      for (int f = 0; f < 4; f++)
        #pragma unroll
        for (int r = 0; r < 4; r++)
          if (k0 + f * 16 + ln > qw + g * 4 + r) sc[f][r] = -1e30f;
    }
    // per-row tile max
    float mx[4];
    #pragma unroll
    for (int r = 0; r < 4; r++){
      float t = fmaxf(fmaxf(sc[0][r], sc[1][r]), fmaxf(sc[2][r], sc[3][r]));
      #pragma unroll
      for (int d = 1; d < 16; d <<= 1) t = fmaxf(t, __shfl_xor(t, d));
      mx[r] = t;
    }
    // defer-max: only rescale when some row grew past THR (log2 units)
    int ok = (mx[0] <= m_r[0] + RESCALE_THR2) & (mx[1] <= m_r[1] + RESCALE_THR2)
           & (mx[2] <= m_r[2] + RESCALE_THR2) & (mx[3] <= m_r[3] + RESCALE_THR2);
    if (!__all(ok)){
      float sf_[4];
      #pragma unroll
      for (int r = 0; r < 4; r++){
        float mn = fmaxf(m_r[r], mx[r]);
        sf_[r] = exp2f(m_r[r] - mn);
        m_r[r] = mn;
      }
      #pragma unroll
      for (int fn = 0; fn < 9; fn++)
        #pragma unroll
        for (int r = 0; r < 4; r++) O[fn][r] *= sf_[r];
    }
    // P = exp2(s - m), store bf16 (swizzled) for PV A-frag
    u16* Pw = Ps[w];
    #pragma unroll
    for (int r = 0; r < 4; r++){
      const int row = g * 4 + r;
      #pragma unroll
      for (int f = 0; f < 4; f++){
        float p = exp2f(sc[f][r] - m_r[r]);
        Pw[row * 64 + ((f * 16 + ln) ^ ((row & 7) << 3))] = f2bf(p);
      }
    }
    // PV (9 fragments; fn=8 hits the ones-row -> l): wave-local LDS
    const u16* Vc = Vs[cur];
    bf16x8 pa0 = *(const bf16x8*)&Pw[ln * 64 + ((g * 8)      ^ ((ln & 7) << 3))];
    bf16x8 pa1 = *(const bf16x8*)&Pw[ln * 64 + ((32 + g * 8) ^ ((ln & 7) << 3))];
    __builtin_amdgcn_s_setprio(1);
    #pragma unroll
    for (int fn = 0; fn < 9; fn++){
      const int vr = fn * 16 + ln;
      bf16x8 v0 = *(const bf16x8*)&Vc[vr * 64 + ((g * 8)      ^ ((ln & 7) << 3))];
      bf16x8 v1 = *(const bf16x8*)&Vc[vr * 64 + ((32 + g * 8) ^ ((ln & 7) << 3))];
      O[fn] = __builtin_amdgcn_mfma_f32_16x16x32_bf16(pa0, v0, O[fn], 0, 0, 0);
      O[fn] = __builtin_amdgcn_mfma_f32_16x16x32_bf16(pa1, v1, O[fn], 0, 0, 0);
    }
    __builtin_amdgcn_s_setprio(0);

    __syncthreads();   // ONE barrier/tile: drains prefetch vmcnt + guards reuse
    cur ^= 1;
  }
  // l (incl. sink term via init) lives in O[8][r] of lanes ln==0
  #pragma unroll
  for (int r = 0; r < 4; r++){
    float l = __shfl(O[8][r], lane & 48);
    float osc = 1.f / l;
    #pragma unroll
    for (int fn = 0; fn < 8; fn++)
      AO[(size_t)(qw + g * 4 + r) * AOST + h * HD + fn * 16 + ln] = f2bf(O[fn][r] * osc);
  }
}

// ---------------- host-side launch ----------------
extern "C" void kernel_launch(void* const* d_in, const int* in_sizes, int n_in,
                              void* d_out, int out_size, void* d_ws, size_t ws_size,
                              hipStream_t stream){
  (void)in_sizes; (void)n_in; (void)out_size; (void)ws_size;
  const float* hs    = (const float*)d_in[0];
  const float* cosv  = (const float*)d_in[1];
  const float* sinv  = (const float*)d_in[2];
  /* d_in[3] attention_mask: pure causal triu(NEG,1) - implemented directly */
  const float* Wq    = (const float*)d_in[4];
  const float* Wk    = (const float*)d_in[5];
  const float* Wv    = (const float*)d_in[6];
  const float* Wo    = (const float*)d_in[7];
  const float* sinkb = (const float*)d_in[8];
  float* out = (float*)d_out;

  char* ws = (char*)d_ws;
  u16* XB    = (u16*)(ws);                  //  8,388,608  X bf16 [2048][2048]
  u16* WQKVB = (u16*)(ws + 8388608);        // 25,165,824  Wqkv bf16 [6144][2048]
  u16* WOB   = (u16*)(ws + 33554432);       // 16,777,216  Wo bf16 [2048][4096]
  u16* QKV   = (u16*)(ws + 50331648);       // 25,165,824  QKV bf16 [2048][6144]
  u16* VT    = (u16*)(ws + 75497472);       //  4,194,304  V^T bf16 [8][128][2048]
  u16* AO    = (u16*)(ws + 79691776);       // 16,777,216  attn out bf16 [2048][4096]

  // single fused convert: hs|Wq|Wk|Wv|Wo -> XB|WQKVB|WOB (contiguous in ws)
  cvt_all_kernel<<<24576, 256, 0, stream>>>((const f32x4*)hs, (const f32x4*)Wq,
                                            (const f32x4*)Wk, (const f32x4*)Wv,
                                            (const f32x4*)Wo, (u16x4*)ws);

  // fused QKV projection + RoPE + Q-scale(log2e) epilogue: [2048][6144]
  gemm_bt_kernel<1, 1, 128><<<dim3(48, 16), 256, 0, stream>>>(XB, WQKVB, QKV, 2048, 6144, 2048, cosv, sinv);

  // V transpose (V region carries no rope)
  vtrans_kernel<<<8192, 256, 0, stream>>>(QKV, VT);

  // attention: flat 1024-block grid (64 q-rows/block), XCD-aligned kvh
  attn_kernel<<<dim3(1024), 256, 0, stream>>>(QKV, VT, sinkb, AO);

  // output projection (f32 out): BN=64 -> 512 blocks (2/CU rolling; the
  // 128x128 grid was 256 blocks = 1/CU, no inter-block drain overlap)
  gemm_bt_kernel<0, 0, 64><<<dim3(32, 16), 256, 0, stream>>>(AO, WOB, out, 2048, 2048, 4096, nullptr, nullptr);
}